// Round 3
// baseline (3082.728 us; speedup 1.0000x reference)
//
#include <hip/hip_runtime.h>

#define HID 64
#define STRIDE 128  // dst nodes per bucket
typedef unsigned long long u64;

// ---------------------------------------------------------------- degree
__global__ __launch_bounds__(256) void count_deg(const int* __restrict__ dst,
                                                 int* __restrict__ deg, int E) {
  int i = blockIdx.x * 256 + threadIdx.x;
  const int stride = gridDim.x * 256;
  for (; i < E; i += stride) atomicAdd(&deg[dst[i]], 1);
}

__global__ __launch_bounds__(256) void compute_dinv(const int* __restrict__ deg,
                                                    float* __restrict__ dinv, int n) {
  const int i = blockIdx.x * 256 + threadIdx.x;
  if (i < n) dinv[i] = rsqrtf((float)(deg[i] + 1));  // +1 self-loop
}

// ---------------------------------------------------------------- scan (rowptr)
__global__ __launch_bounds__(256) void scan_blocks(const int* __restrict__ deg,
                                                   int* __restrict__ rowptr,
                                                   int* __restrict__ bsum, int n) {
  __shared__ int s[256];
  const int t = threadIdx.x;
  const int i = blockIdx.x * 256 + t;
  const int v = (i < n) ? deg[i] : 0;
  s[t] = v;
  __syncthreads();
  for (int off = 1; off < 256; off <<= 1) {
    const int u = (t >= off) ? s[t - off] : 0;
    __syncthreads();
    s[t] += u;
    __syncthreads();
  }
  if (i < n) rowptr[i] = s[t] - v;
  if (t == 255) bsum[blockIdx.x] = s[255];
}

__global__ __launch_bounds__(512) void scan_top(int* bsum, int nb) {
  __shared__ int s[512];
  const int t = threadIdx.x;
  const int v = (t < nb) ? bsum[t] : 0;
  s[t] = v;
  __syncthreads();
  for (int off = 1; off < 512; off <<= 1) {
    const int u = (t >= off) ? s[t - off] : 0;
    __syncthreads();
    s[t] += u;
    __syncthreads();
  }
  if (t < nb) bsum[t] = s[t] - v;
}

__global__ __launch_bounds__(256) void add_offsets(int* __restrict__ rowptr,
                                                   const int* __restrict__ bsum,
                                                   int n, int E) {
  const int i = blockIdx.x * 256 + threadIdx.x;
  if (i < n) rowptr[i] += bsum[blockIdx.x];
  if (i == 0) rowptr[n] = E;
}

// ---------------------------------------------------------------- bucket offsets + cursors
__global__ __launch_bounds__(256) void make_boffs(const int* __restrict__ rowptr,
                                                  int* __restrict__ boffs,
                                                  int* __restrict__ cur,
                                                  int nb, int n, int E) {
  const int b = blockIdx.x * 256 + threadIdx.x;
  if (b < nb) {
    const int v = rowptr[min(b * STRIDE, n)];
    boffs[b] = v;
    cur[b * 16] = v;  // 64B-padded cursor: one L2 line per bucket
  }
  if (b == nb) boffs[nb] = E;
}

// ---------------------------------------------------------------- bucket the edges
// writes cluster at 782 cursor fronts (50 KB working set) -> dense writebacks
__global__ __launch_bounds__(256) void bucket_edges(const int* __restrict__ src,
                                                    const int* __restrict__ dst,
                                                    int* __restrict__ cur,
                                                    u64* __restrict__ pairs, int E) {
  int i = blockIdx.x * 256 + threadIdx.x;
  const int stride = gridDim.x * 256;
  for (; i < E; i += stride) {
    const int d = dst[i];
    const int b = d >> 7;  // d / STRIDE
    const int p = atomicAdd(&cur[b * 16], 1);
    pairs[p] = ((u64)(d & (STRIDE - 1)) << 32) | (unsigned)src[i];
  }
}

// ---------------------------------------------------------------- dense transform
// out[i, c] = dinv[i] * sum_k x[i,k] * W[k,c]
template <int K>
__global__ __launch_bounds__(256) void gemm_nodes(const float* __restrict__ x,
                                                  const float* __restrict__ W,
                                                  const float* __restrict__ dinv,
                                                  float* __restrict__ out) {
  __shared__ float Wl[K * 64];
  __shared__ float xl[16][K];
  const int tid = threadIdx.x;
  for (int i = tid; i < K * 16; i += 256)
    reinterpret_cast<float4*>(Wl)[i] = reinterpret_cast<const float4*>(W)[i];
  const int row0 = blockIdx.x * 16;
  for (int i = tid; i < 16 * (K / 4); i += 256) {
    const int r = i / (K / 4), q = i % (K / 4);
    reinterpret_cast<float4*>(&xl[r][0])[q] =
        reinterpret_cast<const float4*>(x + (size_t)(row0 + r) * K)[q];
  }
  __syncthreads();
  const int c = tid & 63;
  const int rbase = tid >> 6;
  for (int rr = rbase; rr < 16; rr += 4) {
    float acc = 0.f;
#pragma unroll
    for (int k = 0; k < K; k += 4) {
      const float4 xv = *reinterpret_cast<const float4*>(&xl[rr][k]);
      acc = fmaf(xv.x, Wl[(k + 0) * 64 + c], acc);
      acc = fmaf(xv.y, Wl[(k + 1) * 64 + c], acc);
      acc = fmaf(xv.z, Wl[(k + 2) * 64 + c], acc);
      acc = fmaf(xv.w, Wl[(k + 3) * 64 + c], acc);
    }
    const int grow = row0 + rr;
    out[(size_t)grow * 64 + c] = acc * dinv[grow];
  }
}

// ---------------------------------------------------------------- fused bucket aggregation
// out[d,:] = relu(dinv[d]*(sum_{s->d} g[s,:] + g[d,:]) + bias)
__global__ __launch_bounds__(512) void bucket_agg(const u64* __restrict__ pairs,
                                                  const int* __restrict__ boffs,
                                                  const float* __restrict__ g,
                                                  const float* __restrict__ dinv,
                                                  const float* __restrict__ bias,
                                                  float* __restrict__ out, int n) {
  __shared__ float acc[STRIDE][HID];  // 32 KB
  const int tid = threadIdx.x;
  const int bkt = blockIdx.x;
  const int base = bkt * STRIDE;
  for (int i = tid; i < STRIDE * HID / 4; i += 512)
    reinterpret_cast<float4*>(&acc[0][0])[i] = float4{0.f, 0.f, 0.f, 0.f};
  __syncthreads();
  const int beg = boffs[bkt], end = boffs[bkt + 1];
  const int lane = tid & 63, wv = tid >> 6;  // 8 waves
  const int cnt = end - beg;
  const int chunk = (cnt + 7) >> 3;
  int e = beg + wv * chunk;
  const int eend = min(e + chunk, end);
  for (; e + 4 <= eend; e += 4) {  // 4 independent gathers in flight
    const u64 p0 = pairs[e + 0], p1 = pairs[e + 1];
    const u64 p2 = pairs[e + 2], p3 = pairs[e + 3];
    const float v0 = g[(size_t)(unsigned)p0 * HID + lane];
    const float v1 = g[(size_t)(unsigned)p1 * HID + lane];
    const float v2 = g[(size_t)(unsigned)p2 * HID + lane];
    const float v3 = g[(size_t)(unsigned)p3 * HID + lane];
    atomicAdd(&acc[(int)(p0 >> 32)][lane], v0);  // ds_add_f32, no return
    atomicAdd(&acc[(int)(p1 >> 32)][lane], v1);
    atomicAdd(&acc[(int)(p2 >> 32)][lane], v2);
    atomicAdd(&acc[(int)(p3 >> 32)][lane], v3);
  }
  for (; e < eend; ++e) {
    const u64 p = pairs[e];
    atomicAdd(&acc[(int)(p >> 32)][lane], g[(size_t)(unsigned)p * HID + lane]);
  }
  __syncthreads();
  const float bl = bias[lane];
  for (int r = wv; r < STRIDE; r += 8) {
    const int node = base + r;
    if (node >= n) break;
    const float s = acc[r][lane] + g[(size_t)node * HID + lane];  // + self-loop
    out[(size_t)node * HID + lane] = fmaxf(fmaf(s, dinv[node], bl), 0.f);
  }
}

// ---------------------------------------------------------------- final FC (64 -> 11)
__global__ __launch_bounds__(256) void gemm_fc(const float* __restrict__ h,
                                               const float* __restrict__ W,
                                               const float* __restrict__ b,
                                               float* __restrict__ out) {
  __shared__ float Wl[772];
  __shared__ float xl[16][68];
  const int tid = threadIdx.x;
  for (int i = tid; i < 772; i += 256) Wl[i] = 0.f;
  __syncthreads();
  for (int i = tid; i < 64 * 11; i += 256) Wl[(i / 11) * 12 + (i % 11)] = W[i];
  const int row0 = blockIdx.x * 16;
  for (int i = tid; i < 16 * 16; i += 256) {
    const int r = i >> 4, q = i & 15;
    const float4 v = reinterpret_cast<const float4*>(h + (size_t)(row0 + r) * 64)[q];
    xl[r][q * 4 + 0] = v.x; xl[r][q * 4 + 1] = v.y;
    xl[r][q * 4 + 2] = v.z; xl[r][q * 4 + 3] = v.w;
  }
  __syncthreads();
  const int r = tid >> 4, c = tid & 15;
  float acc = 0.f;
#pragma unroll
  for (int k = 0; k < 64; k += 4) {
    acc = fmaf(xl[r][k + 0], Wl[(k + 0) * 12 + c], acc);
    acc = fmaf(xl[r][k + 1], Wl[(k + 1) * 12 + c], acc);
    acc = fmaf(xl[r][k + 2], Wl[(k + 2) * 12 + c], acc);
    acc = fmaf(xl[r][k + 3], Wl[(k + 3) * 12 + c], acc);
  }
  if (c < 11) out[(size_t)(row0 + r) * 11 + c] = acc + b[c];
}

// ---------------------------------------------------------------- launch
extern "C" void kernel_launch(void* const* d_in, const int* in_sizes, int n_in,
                              void* d_out, int out_size, void* d_ws, size_t ws_size,
                              hipStream_t stream) {
  const float* x   = (const float*)d_in[0];
  const int*   ei  = (const int*)d_in[1];   // [2, E] int32
  const float* W1  = (const float*)d_in[2];
  const float* b1  = (const float*)d_in[3];
  const float* W2  = (const float*)d_in[4];
  const float* b2  = (const float*)d_in[5];
  const float* Wfc = (const float*)d_in[6];
  const float* bfc = (const float*)d_in[7];
  float* out = (float*)d_out;

  const int n = in_sizes[0] / 128;  // 100000
  const int E = in_sizes[1] / 2;    // 3200000
  const int* src = ei;
  const int* dst = ei + E;
  const int nbk = (n + STRIDE - 1) / STRIDE;  // 782 buckets

  char* ws = (char*)d_ws;
  size_t o = 0;
  auto alloc = [&](size_t bytes) {
    char* p = ws + o;
    o += (bytes + 255) & ~(size_t)255;
    return p;
  };
  int*   deg    = (int*)  alloc((size_t)n * 4);
  float* dinv   = (float*)alloc((size_t)n * 4);
  int*   rowptr = (int*)  alloc((size_t)(n + 1) * 4);
  int*   bsum   = (int*)  alloc(512 * 4);
  int*   boffs  = (int*)  alloc((size_t)(nbk + 1) * 4);
  int*   cur    = (int*)  alloc((size_t)nbk * 16 * 4);  // 64B-padded cursors
  u64*   pairs  = (u64*)  alloc((size_t)E * 8);
  float* B0     = (float*)alloc((size_t)n * HID * 4);
  float* B1     = (float*)alloc((size_t)n * HID * 4);
  if (o > ws_size) return;

  const int nb = (n + 255) / 256;  // 391 scan blocks
  const int gblocks = n / 16;      // 6250 gemm blocks

  // ---- graph preprocessing (shared by both layers)
  hipMemsetAsync(deg, 0, (size_t)n * 4, stream);
  count_deg<<<2048, 256, 0, stream>>>(dst, deg, E);
  compute_dinv<<<nb, 256, 0, stream>>>(deg, dinv, n);
  scan_blocks<<<nb, 256, 0, stream>>>(deg, rowptr, bsum, n);
  scan_top<<<1, 512, 0, stream>>>(bsum, nb);
  add_offsets<<<nb, 256, 0, stream>>>(rowptr, bsum, n, E);
  make_boffs<<<(nbk + 256) / 256, 256, 0, stream>>>(rowptr, boffs, cur, nbk, n, E);
  bucket_edges<<<4096, 256, 0, stream>>>(src, dst, cur, pairs, E);

  // ---- layer 1
  gemm_nodes<128><<<gblocks, 256, 0, stream>>>(x, W1, dinv, B0);
  bucket_agg<<<nbk, 512, 0, stream>>>(pairs, boffs, B0, dinv, b1, B1, n);

  // ---- layer 2
  gemm_nodes<64><<<gblocks, 256, 0, stream>>>(B1, W2, dinv, B0);
  bucket_agg<<<nbk, 512, 0, stream>>>(pairs, boffs, B0, dinv, b2, B1, n);

  // ---- FC head
  gemm_fc<<<gblocks, 256, 0, stream>>>(B1, Wfc, bfc, out);
}

// Round 4
// 661.439 us; speedup vs baseline: 4.6606x; 4.6606x over previous
//
#include <hip/hip_runtime.h>

#define HID 64
#define STRIDE 128  // dst nodes per bucket
typedef unsigned int u32;

// ---------------------------------------------------------------- degree
__global__ __launch_bounds__(256) void count_deg(const int* __restrict__ dst,
                                                 int* __restrict__ deg, int E) {
  int i = blockIdx.x * 256 + threadIdx.x;
  const int stride = gridDim.x * 256;
  for (; i < E; i += stride) atomicAdd(&deg[dst[i]], 1);
}

__global__ __launch_bounds__(256) void compute_dinv(const int* __restrict__ deg,
                                                    float* __restrict__ dinv, int n) {
  const int i = blockIdx.x * 256 + threadIdx.x;
  if (i < n) dinv[i] = rsqrtf((float)(deg[i] + 1));  // +1 self-loop
}

// ---------------------------------------------------------------- scan (rowptr)
__global__ __launch_bounds__(256) void scan_blocks(const int* __restrict__ deg,
                                                   int* __restrict__ rowptr,
                                                   int* __restrict__ bsum, int n) {
  __shared__ int s[256];
  const int t = threadIdx.x;
  const int i = blockIdx.x * 256 + t;
  const int v = (i < n) ? deg[i] : 0;
  s[t] = v;
  __syncthreads();
  for (int off = 1; off < 256; off <<= 1) {
    const int u = (t >= off) ? s[t - off] : 0;
    __syncthreads();
    s[t] += u;
    __syncthreads();
  }
  if (i < n) rowptr[i] = s[t] - v;
  if (t == 255) bsum[blockIdx.x] = s[255];
}

__global__ __launch_bounds__(512) void scan_top(int* bsum, int nb) {
  __shared__ int s[512];
  const int t = threadIdx.x;
  const int v = (t < nb) ? bsum[t] : 0;
  s[t] = v;
  __syncthreads();
  for (int off = 1; off < 512; off <<= 1) {
    const int u = (t >= off) ? s[t - off] : 0;
    __syncthreads();
    s[t] += u;
    __syncthreads();
  }
  if (t < nb) bsum[t] = s[t] - v;
}

__global__ __launch_bounds__(256) void add_offsets(int* __restrict__ rowptr,
                                                   const int* __restrict__ bsum,
                                                   int n, int E) {
  const int i = blockIdx.x * 256 + threadIdx.x;
  if (i < n) rowptr[i] += bsum[blockIdx.x];
  if (i == 0) rowptr[n] = E;
}

// ---------------------------------------------------------------- bucket offsets + cursors
__global__ __launch_bounds__(256) void make_boffs(const int* __restrict__ rowptr,
                                                  int* __restrict__ boffs,
                                                  int* __restrict__ cur,
                                                  int nbk, int n, int E) {
  const int b = blockIdx.x * 256 + threadIdx.x;
  if (b < nbk) {
    const int v = rowptr[min(b * STRIDE, n)];
    boffs[b] = v;
    cur[b * 16] = v;  // 64B-padded cursor: one L2 line per bucket
  }
  if (b == nbk) boffs[nbk] = E;
}

// ---------------------------------------------------------------- phase 1: bucket edges
// packed u32: (dstLocal<<17) | src   (src < 2^17, dstLocal < 128)
// writes cluster at 782 cursor fronts (50 KB live lines) -> full-line writebacks
__global__ __launch_bounds__(256) void bucket_edges(const int* __restrict__ src,
                                                    const int* __restrict__ dst,
                                                    int* __restrict__ cur,
                                                    u32* __restrict__ pairs, int E) {
  int i = blockIdx.x * 256 + threadIdx.x;
  const int stride = gridDim.x * 256;
  for (; i < E; i += stride) {
    const int d = dst[i];
    const int p = atomicAdd(&cur[(d >> 7) * 16], 1);
    pairs[p] = ((u32)(d & (STRIDE - 1)) << 17) | (u32)src[i];
  }
}

// ---------------------------------------------------------------- phase 2: exact CSR fill
// one block per bucket; writes land in the bucket's contiguous ~16KB colidx window
__global__ __launch_bounds__(256) void local_fill(const u32* __restrict__ pairs,
                                                  const int* __restrict__ boffs,
                                                  const int* __restrict__ rowptr,
                                                  int* __restrict__ colidx, int n) {
  __shared__ int lcur[STRIDE];
  const int bkt = blockIdx.x;
  const int base = bkt * STRIDE;
  const int t = threadIdx.x;
  if (t < STRIDE) {
    const int node = base + t;
    lcur[t] = (node < n) ? rowptr[node] : 0;
  }
  __syncthreads();
  const int beg = boffs[bkt], end = boffs[bkt + 1];
  for (int e = beg + t; e < end; e += 256) {
    const u32 p = pairs[e];
    const int pos = atomicAdd(&lcur[p >> 17], 1);
    colidx[pos] = (int)(p & 0x1FFFF);
  }
}

// ---------------------------------------------------------------- dense transform
// out[i, c] = dinv[i] * sum_k x[i,k] * W[k,c]
template <int K>
__global__ __launch_bounds__(256) void gemm_nodes(const float* __restrict__ x,
                                                  const float* __restrict__ W,
                                                  const float* __restrict__ dinv,
                                                  float* __restrict__ out) {
  __shared__ float Wl[K * 64];
  __shared__ float xl[16][K];
  const int tid = threadIdx.x;
  for (int i = tid; i < K * 16; i += 256)
    reinterpret_cast<float4*>(Wl)[i] = reinterpret_cast<const float4*>(W)[i];
  const int row0 = blockIdx.x * 16;
  for (int i = tid; i < 16 * (K / 4); i += 256) {
    const int r = i / (K / 4), q = i % (K / 4);
    reinterpret_cast<float4*>(&xl[r][0])[q] =
        reinterpret_cast<const float4*>(x + (size_t)(row0 + r) * K)[q];
  }
  __syncthreads();
  const int c = tid & 63;
  const int rbase = tid >> 6;
  for (int rr = rbase; rr < 16; rr += 4) {
    float acc = 0.f;
#pragma unroll
    for (int k = 0; k < K; k += 4) {
      const float4 xv = *reinterpret_cast<const float4*>(&xl[rr][k]);
      acc = fmaf(xv.x, Wl[(k + 0) * 64 + c], acc);
      acc = fmaf(xv.y, Wl[(k + 1) * 64 + c], acc);
      acc = fmaf(xv.z, Wl[(k + 2) * 64 + c], acc);
      acc = fmaf(xv.w, Wl[(k + 3) * 64 + c], acc);
    }
    const int grow = row0 + rr;
    out[(size_t)grow * 64 + c] = acc * dinv[grow];
  }
}

// ---------------------------------------------------------------- pull aggregation
// out[d,lane] = relu( dinv[d] * (sum_{s in N(d)} g[s,lane] + g[d,lane]) + b[lane] )
__global__ __launch_bounds__(256) void gather_agg(const int* __restrict__ rowptr,
                                                  const int* __restrict__ colidx,
                                                  const float* __restrict__ g,
                                                  const float* __restrict__ dinv,
                                                  const float* __restrict__ b,
                                                  float* __restrict__ out, int n) {
  const int lane = threadIdx.x & 63;
  const int node = (blockIdx.x * 256 + threadIdx.x) >> 6;
  if (node >= n) return;
  const int beg = rowptr[node];
  const int end = rowptr[node + 1];
  float acc = 0.f;
  int e = beg;
  for (; e + 4 <= end; e += 4) {  // 4-deep ILP to hide gather latency
    const int s0 = colidx[e + 0], s1 = colidx[e + 1];
    const int s2 = colidx[e + 2], s3 = colidx[e + 3];
    const float v0 = g[(size_t)s0 * HID + lane];
    const float v1 = g[(size_t)s1 * HID + lane];
    const float v2 = g[(size_t)s2 * HID + lane];
    const float v3 = g[(size_t)s3 * HID + lane];
    acc += (v0 + v1) + (v2 + v3);
  }
  for (; e < end; ++e) acc += g[(size_t)colidx[e] * HID + lane];
  acc += g[(size_t)node * HID + lane];  // self-loop (dinv[node]-scaled already)
  const float r = fmaf(acc, dinv[node], b[lane]);
  out[(size_t)node * HID + lane] = fmaxf(r, 0.f);
}

// ---------------------------------------------------------------- final FC (64 -> 11)
__global__ __launch_bounds__(256) void gemm_fc(const float* __restrict__ h,
                                               const float* __restrict__ W,
                                               const float* __restrict__ b,
                                               float* __restrict__ out) {
  __shared__ float Wl[772];
  __shared__ float xl[16][68];
  const int tid = threadIdx.x;
  for (int i = tid; i < 772; i += 256) Wl[i] = 0.f;
  __syncthreads();
  for (int i = tid; i < 64 * 11; i += 256) Wl[(i / 11) * 12 + (i % 11)] = W[i];
  const int row0 = blockIdx.x * 16;
  for (int i = tid; i < 16 * 16; i += 256) {
    const int r = i >> 4, q = i & 15;
    const float4 v = reinterpret_cast<const float4*>(h + (size_t)(row0 + r) * 64)[q];
    xl[r][q * 4 + 0] = v.x; xl[r][q * 4 + 1] = v.y;
    xl[r][q * 4 + 2] = v.z; xl[r][q * 4 + 3] = v.w;
  }
  __syncthreads();
  const int r = tid >> 4, c = tid & 15;
  float acc = 0.f;
#pragma unroll
  for (int k = 0; k < 64; k += 4) {
    acc = fmaf(xl[r][k + 0], Wl[(k + 0) * 12 + c], acc);
    acc = fmaf(xl[r][k + 1], Wl[(k + 1) * 12 + c], acc);
    acc = fmaf(xl[r][k + 2], Wl[(k + 2) * 12 + c], acc);
    acc = fmaf(xl[r][k + 3], Wl[(k + 3) * 12 + c], acc);
  }
  if (c < 11) out[(size_t)(row0 + r) * 11 + c] = acc + b[c];
}

// ---------------------------------------------------------------- launch
extern "C" void kernel_launch(void* const* d_in, const int* in_sizes, int n_in,
                              void* d_out, int out_size, void* d_ws, size_t ws_size,
                              hipStream_t stream) {
  const float* x   = (const float*)d_in[0];
  const int*   ei  = (const int*)d_in[1];   // [2, E] int32
  const float* W1  = (const float*)d_in[2];
  const float* b1  = (const float*)d_in[3];
  const float* W2  = (const float*)d_in[4];
  const float* b2  = (const float*)d_in[5];
  const float* Wfc = (const float*)d_in[6];
  const float* bfc = (const float*)d_in[7];
  float* out = (float*)d_out;

  const int n = in_sizes[0] / 128;  // 100000
  const int E = in_sizes[1] / 2;    // 3200000
  const int* src = ei;
  const int* dst = ei + E;
  const int nbk = (n + STRIDE - 1) / STRIDE;  // 782 buckets

  char* ws = (char*)d_ws;
  size_t o = 0;
  auto alloc = [&](size_t bytes) {
    char* p = ws + o;
    o += (bytes + 255) & ~(size_t)255;
    return p;
  };
  int*   deg    = (int*)  alloc((size_t)n * 4);
  float* dinv   = (float*)alloc((size_t)n * 4);
  int*   rowptr = (int*)  alloc((size_t)(n + 1) * 4);
  int*   bsum   = (int*)  alloc(512 * 4);
  int*   boffs  = (int*)  alloc((size_t)(nbk + 1) * 4);
  int*   cur    = (int*)  alloc((size_t)nbk * 16 * 4);  // 64B-padded cursors
  u32*   pairs  = (u32*)  alloc((size_t)E * 4);
  int*   colidx = (int*)  alloc((size_t)E * 4);
  float* B0     = (float*)alloc((size_t)n * HID * 4);
  float* B1     = (float*)alloc((size_t)n * HID * 4);
  if (o > ws_size) return;

  const int nb = (n + 255) / 256;  // 391 scan blocks
  const int gblocks = n / 16;      // 6250 gemm blocks

  // ---- graph preprocessing (shared by both layers)
  hipMemsetAsync(deg, 0, (size_t)n * 4, stream);
  count_deg<<<2048, 256, 0, stream>>>(dst, deg, E);
  compute_dinv<<<nb, 256, 0, stream>>>(deg, dinv, n);
  scan_blocks<<<nb, 256, 0, stream>>>(deg, rowptr, bsum, n);
  scan_top<<<1, 512, 0, stream>>>(bsum, nb);
  add_offsets<<<nb, 256, 0, stream>>>(rowptr, bsum, n, E);
  make_boffs<<<(nbk + 256) / 256, 256, 0, stream>>>(rowptr, boffs, cur, nbk, n, E);
  bucket_edges<<<4096, 256, 0, stream>>>(src, dst, cur, pairs, E);
  local_fill<<<nbk, 256, 0, stream>>>(pairs, boffs, rowptr, colidx, n);

  const int pull_blocks = (n * 64 + 255) / 256;  // one wave per node

  // ---- layer 1
  gemm_nodes<128><<<gblocks, 256, 0, stream>>>(x, W1, dinv, B0);
  gather_agg<<<pull_blocks, 256, 0, stream>>>(rowptr, colidx, B0, dinv, b1, B1, n);

  // ---- layer 2
  gemm_nodes<64><<<gblocks, 256, 0, stream>>>(B1, W2, dinv, B0);
  gather_agg<<<pull_blocks, 256, 0, stream>>>(rowptr, colidx, B0, dinv, b2, B1, n);

  // ---- FC head
  gemm_fc<<<gblocks, 256, 0, stream>>>(B1, Wfc, bfc, out);
}